// Round 3
// baseline (229.240 us; speedup 1.0000x reference)
//
#include <hip/hip_runtime.h>
#include <hip/hip_bf16.h>

// Problem constants (QREncoder: path signature depth 4 + linear head)
#define BATCH 64
#define LSEQ 256
#define CIN 7
#define CC 8           // channels incl. time
#define NSIG 4680      // 8 + 64 + 512 + 4096
#define KPAD 4736      // NSIG padded to multiple of 64
#define TSTEPS 255     // LSEQ - 1
#define ODIM 512
#define NCHUNK 16      // time chunks for sig write parallelism
#define CH 16          // steps per chunk (last chunk: 15)

typedef __attribute__((ext_vector_type(8))) unsigned short ushort8;
typedef __attribute__((ext_vector_type(8))) __bf16 bf16x8;
typedef __attribute__((ext_vector_type(4))) float f32x4;

__device__ __forceinline__ unsigned short f2bf(float x) {
    __hip_bfloat16 h = __float2bfloat16(x);   // RNE
    return *(unsigned short*)&h;
}

#define GLDS16(gp, lp)                                                      \
    __builtin_amdgcn_global_load_lds(                                       \
        (const __attribute__((address_space(1))) void*)(gp),                \
        (__attribute__((address_space(3))) void*)(lp), 16, 0, 0)

// ---------------------------------------------------------------------------
// Signature scan, time-parallel. Grid (NCHUNK, nb). Each thread carries its
// ENTIRE needed state in registers: a1[i1], a2[i1,i2], a3[tid], a4[8*tid..+8)
// -- all increments derive from the broadcast dx, so there is no cross-thread
// communication and no barrier in the scan. Each block replays the recurrence
// from t=0 (cheap: ~25 VALU/step) and writes only its own chunk's rows, so
// row writes come from the whole machine instead of 64 CUs.
// ---------------------------------------------------------------------------
__global__ __launch_bounds__(512) void sig_kernel(const float* __restrict__ inp,
                                                  unsigned short* __restrict__ sig) {
    __shared__ float sDx[TSTEPS * CC];

    const int chunk = blockIdx.x;              // 0..15
    const int b     = blockIdx.y;
    const int tid   = threadIdx.x;
    const int t0    = chunk * CH;
    const int t1    = (chunk == NCHUNK - 1) ? TSTEPS : t0 + CH;

    // stage dx[0..t1): dx[t][0]=1/255, dx[t][c]=inp[t+1][c-1]-inp[t][c-1]
    const float* ip = inp + (size_t)b * LSEQ * CIN;
    for (int i = tid; i < t1 * CC; i += 512) {
        int t = i >> 3, c = i & 7;
        sDx[i] = (c == 0) ? (1.0f / 255.0f)
                          : ip[(t + 1) * CIN + (c - 1)] - ip[t * CIN + (c - 1)];
    }
    __syncthreads();

    const int i1 = tid >> 6;
    const int i2 = (tid >> 3) & 7;
    const int i3 = tid & 7;

    float a1own = 0.0f;       // a1[i1]
    float a2own = 0.0f;       // a2[i1*8+i2]
    float a3    = 0.0f;       // a3[tid]
    float a4[8];
#pragma unroll
    for (int e = 0; e < 8; ++e) a4[e] = 0.0f;

    // ---- fast-forward t in [0, t0): state update only, no stores ----
    for (int t = 0; t < t0; ++t) {
        const float* v = &sDx[t * CC];
        const float va = v[i1], vb = v[i2], vc = v[i3];
        const float e3s = va * vb * vc * (1.0f / 6.0f);
        const float T4 = e3s * 0.25f + a1own * vb * vc * (1.0f / 6.0f)
                       + a2own * vc * 0.5f + a3;
#pragma unroll
        for (int e = 0; e < 8; ++e) a4[e] += v[e] * T4;
        a3 += e3s + (a1own * vb * 0.5f + a2own) * vc;
        a2own += vb * (0.5f * va + a1own);     // a2[i1,i2] += v[i2]*(v[i1]/2 + a1[i1])
        a1own += va;
    }

    // ---- chunk t in [t0, t1): update + write signature row ----
    for (int t = t0; t < t1; ++t) {
        const float* v = &sDx[t * CC];
        const float va = v[i1], vb = v[i2], vc = v[i3];
        const float e3s = va * vb * vc * (1.0f / 6.0f);
        const float T4 = e3s * 0.25f + a1own * vb * vc * (1.0f / 6.0f)
                       + a2own * vc * 0.5f + a3;
#pragma unroll
        for (int e = 0; e < 8; ++e) a4[e] += v[e] * T4;
        a3 += e3s + (a1own * vb * 0.5f + a2own) * vc;
        a2own += vb * (0.5f * va + a1own);
        a1own += va;

        unsigned short* row = sig + ((size_t)b * TSTEPS + t) * KPAD;
        ushort8 pack;
#pragma unroll
        for (int e = 0; e < 8; ++e) pack[e] = f2bf(a4[e]);
        *(ushort8*)(row + 584 + tid * 8) = pack;       // level 4 [584,4680)
        row[72 + tid] = f2bf(a3);                      // level 3 [72,584)
        if ((tid & 63) == 0) row[i1] = f2bf(a1own);    // level 1 [0,8)
        if ((tid & 7) == 0) row[8 + (tid >> 3)] = f2bf(a2own);  // level 2 [8,72)
        if (tid >= 448 && tid < 504) row[4232 + tid] = 0;       // pad [4680,4736)
    }
}

// ---------------------------------------------------------------------------
// W fp32 [512][4680] -> bf16 [512][KPAD] (pad zeroed)
// ---------------------------------------------------------------------------
__global__ __launch_bounds__(256) void wcvt_kernel(const float* __restrict__ W,
                                                   unsigned short* __restrict__ Wb) {
    int idx = blockIdx.x * 256 + threadIdx.x;
    if (idx >= ODIM * KPAD) return;
    int n = idx / KPAD, k = idx - n * KPAD;
    Wb[idx] = (k < NSIG) ? f2bf(W[(size_t)n * NSIG + k]) : (unsigned short)0;
}

// ---------------------------------------------------------------------------
// MFMA GEMM. out[m][n] = sum_k A[m][k]*Wb[n][k] + bias[n]
// 128x128 tile, BK=64, 4 waves x (64x64, 4x4 frags of 16x16x32 bf16),
// global_load_lds width 16. XCD-grouped swizzle: XCD x = id%8 owns m-panels
// [16x,16x+16), the 4 n-tiles of one m-panel adjacent (A panel fetched into
// exactly one XCD's L2; Wb k-slices stay L2-hot).
// ---------------------------------------------------------------------------
__global__ __launch_bounds__(256) void gemm_kernel(const unsigned short* __restrict__ A,
                                                   const unsigned short* __restrict__ Wb,
                                                   const float* __restrict__ bias,
                                                   float* __restrict__ out,
                                                   int Mrows) {
    __shared__ unsigned short As[128 * 64];   // 16 KB
    __shared__ unsigned short Bs[128 * 64];   // 16 KB

    const int tid  = threadIdx.x;
    int nt, mt;
    if (gridDim.y == 128) {                    // full-size dispatch: swizzle
        const int li = blockIdx.y * 4 + blockIdx.x;   // == hw linear block id
        const int x  = li & 7;                 // XCD (round-robin assumption)
        const int j  = li >> 3;                // 0..63 within XCD
        mt = x * 16 + (j >> 2);                // m-panels grouped per XCD
        nt = j & 3;                            // n fastest: A panel reused in L2
    } else {
        nt = blockIdx.x; mt = blockIdx.y;
    }
    const int lane = tid & 63;
    const int wv   = tid >> 6;
    const int wr   = wv >> 1;
    const int wc   = wv & 1;
    const int lr   = lane & 15;
    const int lk   = (lane >> 4) * 8;

    const f32x4 z = {0.0f, 0.0f, 0.0f, 0.0f};
    f32x4 acc[4][4];
#pragma unroll
    for (int i = 0; i < 4; ++i)
#pragma unroll
        for (int j = 0; j < 4; ++j) acc[i][j] = z;

    const int srow = tid >> 3;
    const int scol = (tid & 7) * 8;

    for (int k0 = 0; k0 < KPAD; k0 += 64) {
#pragma unroll
        for (int i = 0; i < 4; ++i) {
            int gr = mt * 128 + i * 32 + srow;
            if (gr >= Mrows) gr = 0;
            GLDS16(A + (size_t)gr * KPAD + k0 + scol,
                   ((char*)As) + i * 4096 + tid * 16);
            const int gn = nt * 128 + i * 32 + srow;
            GLDS16(Wb + (size_t)gn * KPAD + k0 + scol,
                   ((char*)Bs) + i * 4096 + tid * 16);
        }
        __syncthreads();

#pragma unroll
        for (int ks = 0; ks < 2; ++ks) {
            const int kk = ks * 32 + lk;
            bf16x8 af[4], bf[4];
#pragma unroll
            for (int i = 0; i < 4; ++i)
                af[i] = *(const bf16x8*)&As[(wr * 64 + i * 16 + lr) * 64 + kk];
#pragma unroll
            for (int j = 0; j < 4; ++j)
                bf[j] = *(const bf16x8*)&Bs[(wc * 64 + j * 16 + lr) * 64 + kk];
#pragma unroll
            for (int i = 0; i < 4; ++i)
#pragma unroll
                for (int j = 0; j < 4; ++j)
                    acc[i][j] = __builtin_amdgcn_mfma_f32_16x16x32_bf16(
                        af[i], bf[j], acc[i][j], 0, 0, 0);
        }
        __syncthreads();
    }

    float bn[4];
#pragma unroll
    for (int j = 0; j < 4; ++j)
        bn[j] = bias[nt * 128 + wc * 64 + j * 16 + lr];

#pragma unroll
    for (int i = 0; i < 4; ++i) {
        const int mbase = mt * 128 + wr * 64 + i * 16 + (lane >> 4) * 4;
#pragma unroll
        for (int r = 0; r < 4; ++r) {
            const int m = mbase + r;
            if (m < Mrows) {
#pragma unroll
                for (int j = 0; j < 4; ++j) {
                    const int n = nt * 128 + wc * 64 + j * 16 + lr;
                    out[(size_t)m * ODIM + n] = acc[i][j][r] + bn[j];
                }
            }
        }
    }
}

extern "C" void kernel_launch(void* const* d_in, const int* in_sizes, int n_in,
                              void* d_out, int out_size, void* d_ws, size_t ws_size,
                              hipStream_t stream) {
    const float* inp  = (const float*)d_in[0];
    const float* W    = (const float*)d_in[1];
    const float* bias = (const float*)d_in[2];
    float* out = (float*)d_out;

    const size_t wbBytes  = (size_t)ODIM * KPAD * sizeof(unsigned short);
    const size_t perBatch = (size_t)TSTEPS * KPAD * sizeof(unsigned short);

    unsigned short* sig = (unsigned short*)d_ws;
    unsigned short* Wb  = (unsigned short*)((char*)d_ws + (ws_size - wbBytes));

    int nbMax = (int)((ws_size - wbBytes) / perBatch);
    if (nbMax > BATCH) nbMax = BATCH;
    if (nbMax < 1) nbMax = 1;

    wcvt_kernel<<<(ODIM * KPAD + 255) / 256, 256, 0, stream>>>(W, Wb);

    for (int b0 = 0; b0 < BATCH; b0 += nbMax) {
        const int nb = (b0 + nbMax <= BATCH) ? nbMax : (BATCH - b0);
        const int Mrows = nb * TSTEPS;
        sig_kernel<<<dim3(NCHUNK, nb), 512, 0, stream>>>(
            inp + (size_t)b0 * LSEQ * CIN, sig);
        gemm_kernel<<<dim3(ODIM / 128, (Mrows + 127) / 128), 256, 0, stream>>>(
            sig, Wb, bias, out + (size_t)b0 * TSTEPS * ODIM, Mrows);
    }
}

// Round 4
// 207.797 us; speedup vs baseline: 1.1032x; 1.1032x over previous
//
#include <hip/hip_runtime.h>
#include <hip/hip_bf16.h>

// Problem constants (QREncoder: path signature depth 4 + linear head)
#define BATCH 64
#define LSEQ 256
#define CIN 7
#define CC 8           // channels incl. time
#define NSIG 4680      // 8 + 64 + 512 + 4096
#define KPAD 4736      // NSIG padded to multiple of 64
#define TSTEPS 255     // LSEQ - 1
#define ODIM 512
#define NCHUNK 16      // time chunks for sig write parallelism
#define CH 16          // steps per chunk (last chunk: 15)
#define KHALF 2368     // split-K: 37 K-steps of 64 each

typedef __attribute__((ext_vector_type(8))) unsigned short ushort8;
typedef __attribute__((ext_vector_type(8))) __bf16 bf16x8;
typedef __attribute__((ext_vector_type(4))) float f32x4;

__device__ __forceinline__ unsigned short f2bf(float x) {
    __hip_bfloat16 h = __float2bfloat16(x);   // RNE
    return *(unsigned short*)&h;
}

#define GLDS16(gp, lp)                                                      \
    __builtin_amdgcn_global_load_lds(                                       \
        (const __attribute__((address_space(1))) void*)(gp),                \
        (__attribute__((address_space(3))) void*)(lp), 16, 0, 0)

// ---------------------------------------------------------------------------
// Scan pass A: one block per batch, sequential 255-step state-only scan,
// dumping full state (4680 f32) at t = 16,32,...,240 (15 checkpoints).
// Thread tid carries a1[i1], a2[i1,i2], a3[tid], a4[8t..8t+8) in registers;
// zero cross-thread communication (all increments derive from broadcast dx).
// ---------------------------------------------------------------------------
__global__ __launch_bounds__(512) void sig_ckpt_kernel(const float* __restrict__ inp,
                                                       float* __restrict__ ckpt) {
    __shared__ float sDx[TSTEPS * CC];

    const int b   = blockIdx.x;
    const int tid = threadIdx.x;

    const float* ip = inp + (size_t)b * LSEQ * CIN;
    for (int i = tid; i < TSTEPS * CC; i += 512) {
        int t = i >> 3, c = i & 7;
        sDx[i] = (c == 0) ? (1.0f / 255.0f)
                          : ip[(t + 1) * CIN + (c - 1)] - ip[t * CIN + (c - 1)];
    }
    __syncthreads();

    const int i1 = tid >> 6;
    const int i2 = (tid >> 3) & 7;
    const int i3 = tid & 7;

    float a1own = 0.0f, a2own = 0.0f, a3 = 0.0f;
    float a4[8];
#pragma unroll
    for (int e = 0; e < 8; ++e) a4[e] = 0.0f;

    for (int t = 0; t < 240; ++t) {
        const float* v = &sDx[t * CC];
        const float4 vlo = *(const float4*)&v[0];
        const float4 vhi = *(const float4*)&v[4];
        const float va = v[i1], vb = v[i2], vc = v[i3];
        const float e3s = va * vb * vc * (1.0f / 6.0f);
        const float T4 = e3s * 0.25f + a1own * vb * vc * (1.0f / 6.0f)
                       + a2own * vc * 0.5f + a3;
        a4[0] += vlo.x * T4; a4[1] += vlo.y * T4;
        a4[2] += vlo.z * T4; a4[3] += vlo.w * T4;
        a4[4] += vhi.x * T4; a4[5] += vhi.y * T4;
        a4[6] += vhi.z * T4; a4[7] += vhi.w * T4;
        a3 += e3s + (a1own * vb * 0.5f + a2own) * vc;
        a2own += vb * (0.5f * va + a1own);
        a1own += va;

        if (((t + 1) & 15) == 0) {            // t+1 in {16,...,240}
            const int c = ((t + 1) >> 4) - 1; // 0..14
            float* cp = ckpt + ((size_t)b * 15 + c) * NSIG;
            if ((tid & 63) == 0) cp[i1] = a1own;
            if ((tid & 7) == 0) cp[8 + (tid >> 3)] = a2own;
            cp[72 + tid] = a3;
            float4 q0 = {a4[0], a4[1], a4[2], a4[3]};
            float4 q1 = {a4[4], a4[5], a4[6], a4[7]};
            *(float4*)&cp[584 + tid * 8]     = q0;
            *(float4*)&cp[584 + tid * 8 + 4] = q1;
        }
    }
}

// ---------------------------------------------------------------------------
// Scan pass B: grid (NCHUNK, nb). Block (chunk,b) loads the chunk's start
// state from ckpt (chunk 0: zeros), runs <=16 steps, writes sig rows (bf16).
// ---------------------------------------------------------------------------
__global__ __launch_bounds__(512) void sig_write_kernel(const float* __restrict__ inp,
                                                        const float* __restrict__ ckpt,
                                                        unsigned short* __restrict__ sig) {
    __shared__ float sDx[CH * CC];

    const int chunk = blockIdx.x;
    const int b     = blockIdx.y;
    const int tid   = threadIdx.x;
    const int t0    = chunk * CH;
    const int t1    = (chunk == NCHUNK - 1) ? TSTEPS : t0 + CH;

    const float* ip = inp + (size_t)b * LSEQ * CIN;
    for (int i = tid; i < (t1 - t0) * CC; i += 512) {
        int t = t0 + (i >> 3), c = i & 7;
        sDx[i] = (c == 0) ? (1.0f / 255.0f)
                          : ip[(t + 1) * CIN + (c - 1)] - ip[t * CIN + (c - 1)];
    }
    __syncthreads();

    const int i1 = tid >> 6;
    const int i2 = (tid >> 3) & 7;
    const int i3 = tid & 7;

    float a1own, a2own, a3;
    float a4[8];
    if (chunk == 0) {
        a1own = a2own = a3 = 0.0f;
#pragma unroll
        for (int e = 0; e < 8; ++e) a4[e] = 0.0f;
    } else {
        const float* cp = ckpt + ((size_t)b * 15 + (chunk - 1)) * NSIG;
        a1own = cp[i1];
        a2own = cp[8 + (tid >> 3)];
        a3    = cp[72 + tid];
        float4 q0 = *(const float4*)&cp[584 + tid * 8];
        float4 q1 = *(const float4*)&cp[584 + tid * 8 + 4];
        a4[0] = q0.x; a4[1] = q0.y; a4[2] = q0.z; a4[3] = q0.w;
        a4[4] = q1.x; a4[5] = q1.y; a4[6] = q1.z; a4[7] = q1.w;
    }

    for (int t = t0; t < t1; ++t) {
        const float* v = &sDx[(t - t0) * CC];
        const float4 vlo = *(const float4*)&v[0];
        const float4 vhi = *(const float4*)&v[4];
        const float va = v[i1], vb = v[i2], vc = v[i3];
        const float e3s = va * vb * vc * (1.0f / 6.0f);
        const float T4 = e3s * 0.25f + a1own * vb * vc * (1.0f / 6.0f)
                       + a2own * vc * 0.5f + a3;
        a4[0] += vlo.x * T4; a4[1] += vlo.y * T4;
        a4[2] += vlo.z * T4; a4[3] += vlo.w * T4;
        a4[4] += vhi.x * T4; a4[5] += vhi.y * T4;
        a4[6] += vhi.z * T4; a4[7] += vhi.w * T4;
        a3 += e3s + (a1own * vb * 0.5f + a2own) * vc;
        a2own += vb * (0.5f * va + a1own);
        a1own += va;

        unsigned short* row = sig + ((size_t)b * TSTEPS + t) * KPAD;
        ushort8 pack;
#pragma unroll
        for (int e = 0; e < 8; ++e) pack[e] = f2bf(a4[e]);
        *(ushort8*)(row + 584 + tid * 8) = pack;                // level 4
        row[72 + tid] = f2bf(a3);                               // level 3
        if ((tid & 63) == 0) row[i1] = f2bf(a1own);             // level 1
        if ((tid & 7) == 0) row[8 + (tid >> 3)] = f2bf(a2own);  // level 2
        if (tid >= 448 && tid < 504) row[4232 + tid] = 0;       // pad
    }
}

// ---------------------------------------------------------------------------
// W fp32 [512][4680] -> bf16 [512][KPAD] (pad zeroed)
// ---------------------------------------------------------------------------
__global__ __launch_bounds__(256) void wcvt_kernel(const float* __restrict__ W,
                                                   unsigned short* __restrict__ Wb) {
    int idx = blockIdx.x * 256 + threadIdx.x;
    if (idx >= ODIM * KPAD) return;
    int n = idx / KPAD, k = idx - n * KPAD;
    Wb[idx] = (k < NSIG) ? f2bf(W[(size_t)n * NSIG + k]) : (unsigned short)0;
}

// ---------------------------------------------------------------------------
// MFMA GEMM, split-K=2. part[z][m][n] = sum_{k in half z} A[m][k]*Wb[n][k]
// 128x128 tile, BK=64, 4 waves x (64x64, 4x4 frags of 16x16x32 bf16),
// global_load_lds width 16. blockIdx.z = K-half. Grid 1024 blocks ->
// 4 blocks/CU (was 2). XCD-grouped swizzle within each z-slab (slab = 512
// blocks, multiple of 8, so li%8 is preserved per slab).
// ---------------------------------------------------------------------------
__global__ __launch_bounds__(256) void gemm_kernel(const unsigned short* __restrict__ A,
                                                   const unsigned short* __restrict__ Wb,
                                                   float* __restrict__ part,
                                                   int Mrows) {
    __shared__ unsigned short As[128 * 64];   // 16 KB
    __shared__ unsigned short Bs[128 * 64];   // 16 KB

    const int tid = threadIdx.x;
    const int kz  = blockIdx.z;
    int nt, mt;
    if (gridDim.y == 128) {                    // full-size dispatch: swizzle
        const int li = blockIdx.y * 4 + blockIdx.x;
        const int x  = li & 7;                 // XCD (round-robin assumption)
        const int j  = li >> 3;
        mt = x * 16 + (j >> 2);
        nt = j & 3;
    } else {
        nt = blockIdx.x; mt = blockIdx.y;
    }
    const int lane = tid & 63;
    const int wv   = tid >> 6;
    const int wr   = wv >> 1;
    const int wc   = wv & 1;
    const int lr   = lane & 15;
    const int lk   = (lane >> 4) * 8;

    const f32x4 z4 = {0.0f, 0.0f, 0.0f, 0.0f};
    f32x4 acc[4][4];
#pragma unroll
    for (int i = 0; i < 4; ++i)
#pragma unroll
        for (int j = 0; j < 4; ++j) acc[i][j] = z4;

    const int srow = tid >> 3;
    const int scol = (tid & 7) * 8;

    const int kbeg = kz * KHALF;
    for (int k0 = kbeg; k0 < kbeg + KHALF; k0 += 64) {
#pragma unroll
        for (int i = 0; i < 4; ++i) {
            int gr = mt * 128 + i * 32 + srow;
            if (gr >= Mrows) gr = 0;
            GLDS16(A + (size_t)gr * KPAD + k0 + scol,
                   ((char*)As) + i * 4096 + tid * 16);
            const int gn = nt * 128 + i * 32 + srow;
            GLDS16(Wb + (size_t)gn * KPAD + k0 + scol,
                   ((char*)Bs) + i * 4096 + tid * 16);
        }
        __syncthreads();

#pragma unroll
        for (int ks = 0; ks < 2; ++ks) {
            const int kk = ks * 32 + lk;
            bf16x8 af[4], bf[4];
#pragma unroll
            for (int i = 0; i < 4; ++i)
                af[i] = *(const bf16x8*)&As[(wr * 64 + i * 16 + lr) * 64 + kk];
#pragma unroll
            for (int j = 0; j < 4; ++j)
                bf[j] = *(const bf16x8*)&Bs[(wc * 64 + j * 16 + lr) * 64 + kk];
#pragma unroll
            for (int i = 0; i < 4; ++i)
#pragma unroll
                for (int j = 0; j < 4; ++j)
                    acc[i][j] = __builtin_amdgcn_mfma_f32_16x16x32_bf16(
                        af[i], bf[j], acc[i][j], 0, 0, 0);
        }
        __syncthreads();
    }

    float* po = part + (size_t)kz * Mrows * ODIM;
#pragma unroll
    for (int i = 0; i < 4; ++i) {
        const int mbase = mt * 128 + wr * 64 + i * 16 + (lane >> 4) * 4;
#pragma unroll
        for (int r = 0; r < 4; ++r) {
            const int m = mbase + r;
            if (m < Mrows) {
#pragma unroll
                for (int j = 0; j < 4; ++j) {
                    const int n = nt * 128 + wc * 64 + j * 16 + lr;
                    po[(size_t)m * ODIM + n] = acc[i][j][r];
                }
            }
        }
    }
}

// ---------------------------------------------------------------------------
// out[m][n] = p0[m][n] + p1[m][n] + bias[n]   (float4 vectorized)
// ---------------------------------------------------------------------------
__global__ __launch_bounds__(256) void combine_kernel(const float* __restrict__ part,
                                                      const float* __restrict__ bias,
                                                      float* __restrict__ out,
                                                      int Mrows) {
    const int total = Mrows * (ODIM / 4);
    int idx = blockIdx.x * 256 + threadIdx.x;
    if (idx >= total) return;
    const int m  = idx / (ODIM / 4);
    const int nq = idx - m * (ODIM / 4);
    const size_t off = (size_t)m * ODIM + nq * 4;
    float4 p0 = *(const float4*)(part + off);
    float4 p1 = *(const float4*)(part + (size_t)Mrows * ODIM + off);
    float4 bv = *(const float4*)(bias + nq * 4);
    float4 r = {p0.x + p1.x + bv.x, p0.y + p1.y + bv.y,
                p0.z + p1.z + bv.z, p0.w + p1.w + bv.w};
    *(float4*)(out + off) = r;
}

extern "C" void kernel_launch(void* const* d_in, const int* in_sizes, int n_in,
                              void* d_out, int out_size, void* d_ws, size_t ws_size,
                              hipStream_t stream) {
    const float* inp  = (const float*)d_in[0];
    const float* W    = (const float*)d_in[1];
    const float* bias = (const float*)d_in[2];
    float* out = (float*)d_out;

    const size_t wbBytes = (size_t)ODIM * KPAD * sizeof(unsigned short);
    const size_t sigPB   = (size_t)TSTEPS * KPAD * sizeof(unsigned short); // 2.42 MB
    const size_t ckptPB  = (size_t)15 * NSIG * sizeof(float);              // 0.28 MB
    const size_t partPB  = (size_t)2 * TSTEPS * ODIM * sizeof(float);      // 1.04 MB
    const size_t perB    = sigPB + ckptPB + partPB;

    int nbMax = (int)((ws_size - wbBytes) / perB);
    if (nbMax > BATCH) nbMax = BATCH;
    if (nbMax < 1) nbMax = 1;

    unsigned short* sig  = (unsigned short*)d_ws;
    float*          ckpt = (float*)((char*)d_ws + (size_t)nbMax * sigPB);
    float*          part = (float*)((char*)ckpt + (size_t)nbMax * ckptPB);
    unsigned short* Wb   = (unsigned short*)((char*)d_ws + (ws_size - wbBytes));

    wcvt_kernel<<<(ODIM * KPAD + 255) / 256, 256, 0, stream>>>(W, Wb);

    for (int b0 = 0; b0 < BATCH; b0 += nbMax) {
        const int nb = (b0 + nbMax <= BATCH) ? nbMax : (BATCH - b0);
        const int Mrows = nb * TSTEPS;
        const float* ipb = inp + (size_t)b0 * LSEQ * CIN;
        sig_ckpt_kernel<<<nb, 512, 0, stream>>>(ipb, ckpt);
        sig_write_kernel<<<dim3(NCHUNK, nb), 512, 0, stream>>>(ipb, ckpt, sig);
        gemm_kernel<<<dim3(ODIM / 128, (Mrows + 127) / 128, 2), 256, 0, stream>>>(
            sig, Wb, part, Mrows);
        combine_kernel<<<(Mrows * (ODIM / 4) + 255) / 256, 256, 0, stream>>>(
            part, bias, out + (size_t)b0 * TSTEPS * ODIM, Mrows);
    }
}

// Round 5
// 166.063 us; speedup vs baseline: 1.3804x; 1.2513x over previous
//
#include <hip/hip_runtime.h>
#include <hip/hip_bf16.h>

// Problem constants (QREncoder: path signature depth 4 + linear head)
#define BATCH 64
#define LSEQ 256
#define CIN 7
#define CC 8           // channels incl. time
#define NSIG 4680      // 8 + 64 + 512 + 4096
#define KPAD 4736      // NSIG padded to multiple of 64
#define TSTEPS 255     // LSEQ - 1
#define ODIM 512
#define NCHUNK 16      // time chunks for sig write parallelism
#define CH 16          // steps per chunk (last chunk: 15)

typedef __attribute__((ext_vector_type(8))) unsigned short ushort8;
typedef __attribute__((ext_vector_type(8))) __bf16 bf16x8;
typedef __attribute__((ext_vector_type(4))) float f32x4;

__device__ __forceinline__ unsigned short f2bf(float x) {
    __hip_bfloat16 h = __float2bfloat16(x);   // RNE
    return *(unsigned short*)&h;
}

#define GLDS16(gp, lp)                                                      \
    __builtin_amdgcn_global_load_lds(                                       \
        (const __attribute__((address_space(1))) void*)(gp),                \
        (__attribute__((address_space(3))) void*)(lp), 16, 0, 0)

// ---------------------------------------------------------------------------
// Scan pass A: one block per batch, sequential 255-step state-only scan,
// dumping full state (4680 f32) at t = 16,32,...,240 (15 checkpoints).
// Thread tid carries a1[i1], a2[i1,i2], a3[tid], a4[8t..8t+8) in registers;
// zero cross-thread communication (all increments derive from broadcast dx).
// ---------------------------------------------------------------------------
__global__ __launch_bounds__(512) void sig_ckpt_kernel(const float* __restrict__ inp,
                                                       float* __restrict__ ckpt) {
    __shared__ float sDx[TSTEPS * CC];

    const int b   = blockIdx.x;
    const int tid = threadIdx.x;

    const float* ip = inp + (size_t)b * LSEQ * CIN;
    for (int i = tid; i < TSTEPS * CC; i += 512) {
        int t = i >> 3, c = i & 7;
        sDx[i] = (c == 0) ? (1.0f / 255.0f)
                          : ip[(t + 1) * CIN + (c - 1)] - ip[t * CIN + (c - 1)];
    }
    __syncthreads();

    const int i1 = tid >> 6;
    const int i2 = (tid >> 3) & 7;
    const int i3 = tid & 7;

    float a1own = 0.0f, a2own = 0.0f, a3 = 0.0f;
    float a4[8];
#pragma unroll
    for (int e = 0; e < 8; ++e) a4[e] = 0.0f;

    for (int t = 0; t < 240; ++t) {
        const float* v = &sDx[t * CC];
        const float4 vlo = *(const float4*)&v[0];
        const float4 vhi = *(const float4*)&v[4];
        const float va = v[i1], vb = v[i2], vc = v[i3];
        const float e3s = va * vb * vc * (1.0f / 6.0f);
        const float T4 = e3s * 0.25f + a1own * vb * vc * (1.0f / 6.0f)
                       + a2own * vc * 0.5f + a3;
        a4[0] += vlo.x * T4; a4[1] += vlo.y * T4;
        a4[2] += vlo.z * T4; a4[3] += vlo.w * T4;
        a4[4] += vhi.x * T4; a4[5] += vhi.y * T4;
        a4[6] += vhi.z * T4; a4[7] += vhi.w * T4;
        a3 += e3s + (a1own * vb * 0.5f + a2own) * vc;
        a2own += vb * (0.5f * va + a1own);
        a1own += va;

        if (((t + 1) & 15) == 0) {            // t+1 in {16,...,240}
            const int c = ((t + 1) >> 4) - 1; // 0..14
            float* cp = ckpt + ((size_t)b * 15 + c) * NSIG;
            if ((tid & 63) == 0) cp[i1] = a1own;
            if ((tid & 7) == 0) cp[8 + (tid >> 3)] = a2own;
            cp[72 + tid] = a3;
            float4 q0 = {a4[0], a4[1], a4[2], a4[3]};
            float4 q1 = {a4[4], a4[5], a4[6], a4[7]};
            *(float4*)&cp[584 + tid * 8]     = q0;
            *(float4*)&cp[584 + tid * 8 + 4] = q1;
        }
    }
}

// ---------------------------------------------------------------------------
// Scan pass B: grid (NCHUNK, nb). Block (chunk,b) loads the chunk's start
// state from ckpt (chunk 0: zeros), runs <=16 steps, writes sig rows (bf16).
// ---------------------------------------------------------------------------
__global__ __launch_bounds__(512) void sig_write_kernel(const float* __restrict__ inp,
                                                        const float* __restrict__ ckpt,
                                                        unsigned short* __restrict__ sig) {
    __shared__ float sDx[CH * CC];

    const int chunk = blockIdx.x;
    const int b     = blockIdx.y;
    const int tid   = threadIdx.x;
    const int t0    = chunk * CH;
    const int t1    = (chunk == NCHUNK - 1) ? TSTEPS : t0 + CH;

    const float* ip = inp + (size_t)b * LSEQ * CIN;
    for (int i = tid; i < (t1 - t0) * CC; i += 512) {
        int t = t0 + (i >> 3), c = i & 7;
        sDx[i] = (c == 0) ? (1.0f / 255.0f)
                          : ip[(t + 1) * CIN + (c - 1)] - ip[t * CIN + (c - 1)];
    }
    __syncthreads();

    const int i1 = tid >> 6;
    const int i2 = (tid >> 3) & 7;
    const int i3 = tid & 7;

    float a1own, a2own, a3;
    float a4[8];
    if (chunk == 0) {
        a1own = a2own = a3 = 0.0f;
#pragma unroll
        for (int e = 0; e < 8; ++e) a4[e] = 0.0f;
    } else {
        const float* cp = ckpt + ((size_t)b * 15 + (chunk - 1)) * NSIG;
        a1own = cp[i1];
        a2own = cp[8 + (tid >> 3)];
        a3    = cp[72 + tid];
        float4 q0 = *(const float4*)&cp[584 + tid * 8];
        float4 q1 = *(const float4*)&cp[584 + tid * 8 + 4];
        a4[0] = q0.x; a4[1] = q0.y; a4[2] = q0.z; a4[3] = q0.w;
        a4[4] = q1.x; a4[5] = q1.y; a4[6] = q1.z; a4[7] = q1.w;
    }

    for (int t = t0; t < t1; ++t) {
        const float* v = &sDx[(t - t0) * CC];
        const float4 vlo = *(const float4*)&v[0];
        const float4 vhi = *(const float4*)&v[4];
        const float va = v[i1], vb = v[i2], vc = v[i3];
        const float e3s = va * vb * vc * (1.0f / 6.0f);
        const float T4 = e3s * 0.25f + a1own * vb * vc * (1.0f / 6.0f)
                       + a2own * vc * 0.5f + a3;
        a4[0] += vlo.x * T4; a4[1] += vlo.y * T4;
        a4[2] += vlo.z * T4; a4[3] += vlo.w * T4;
        a4[4] += vhi.x * T4; a4[5] += vhi.y * T4;
        a4[6] += vhi.z * T4; a4[7] += vhi.w * T4;
        a3 += e3s + (a1own * vb * 0.5f + a2own) * vc;
        a2own += vb * (0.5f * va + a1own);
        a1own += va;

        unsigned short* row = sig + ((size_t)b * TSTEPS + t) * KPAD;
        ushort8 pack;
#pragma unroll
        for (int e = 0; e < 8; ++e) pack[e] = f2bf(a4[e]);
        *(ushort8*)(row + 584 + tid * 8) = pack;                // level 4
        row[72 + tid] = f2bf(a3);                               // level 3
        if ((tid & 63) == 0) row[i1] = f2bf(a1own);             // level 1
        if ((tid & 7) == 0) row[8 + (tid >> 3)] = f2bf(a2own);  // level 2
        if (tid >= 448 && tid < 504) row[4232 + tid] = 0;       // pad
    }
}

// ---------------------------------------------------------------------------
// W fp32 [512][4680] -> bf16 [512][KPAD] (pad zeroed)
// ---------------------------------------------------------------------------
__global__ __launch_bounds__(256) void wcvt_kernel(const float* __restrict__ W,
                                                   unsigned short* __restrict__ Wb) {
    int idx = blockIdx.x * 256 + threadIdx.x;
    if (idx >= ODIM * KPAD) return;
    int n = idx / KPAD, k = idx - n * KPAD;
    Wb[idx] = (k < NSIG) ? f2bf(W[(size_t)n * NSIG + k]) : (unsigned short)0;
}

// ---------------------------------------------------------------------------
// MFMA GEMM. out[m][n] = sum_k A[m][k]*Wb[n][k] + bias[n]
// 128x128 tile, BK=64, 4 waves x (64x64, 4x4 frags of 16x16x32 bf16).
// T2 XOR-swizzle (gload_lds-compatible, rule #21): LDS dest stays linear,
// per-lane GLOBAL source 16B-block is pre-swizzled (cb ^= row&7), and the
// ds_read block index applies the same XOR (kb ^ (lr&7); row&7 == lr&7 for
// every fragment row since 16 | frag offsets). Each quarter-wave's b128
// reads then cover all 32 banks (2-way = free) instead of a 16-way pileup.
// XCD-grouped swizzle as before.
// ---------------------------------------------------------------------------
__global__ __launch_bounds__(256) void gemm_kernel(const unsigned short* __restrict__ A,
                                                   const unsigned short* __restrict__ Wb,
                                                   const float* __restrict__ bias,
                                                   float* __restrict__ out,
                                                   int Mrows) {
    __shared__ unsigned short As[128 * 64];   // 16 KB
    __shared__ unsigned short Bs[128 * 64];   // 16 KB

    const int tid = threadIdx.x;
    int nt, mt;
    if (gridDim.y == 128) {                    // full-size dispatch: swizzle
        const int li = blockIdx.y * 4 + blockIdx.x;
        const int x  = li & 7;                 // XCD (round-robin assumption)
        const int j  = li >> 3;
        mt = x * 16 + (j >> 2);
        nt = j & 3;
    } else {
        nt = blockIdx.x; mt = blockIdx.y;
    }
    const int lane = tid & 63;
    const int wv   = tid >> 6;
    const int wr   = wv >> 1;
    const int wc   = wv & 1;
    const int lr   = lane & 15;
    const int lk   = (lane >> 4) * 8;
    const int sb   = lr & 7;                  // read-side swizzle key

    const f32x4 z4 = {0.0f, 0.0f, 0.0f, 0.0f};
    f32x4 acc[4][4];
#pragma unroll
    for (int i = 0; i < 4; ++i)
#pragma unroll
        for (int j = 0; j < 4; ++j) acc[i][j] = z4;

    const int srow = tid >> 3;                          // 0..31
    const int gcb  = (tid & 7) ^ (srow & 7);            // pre-swizzled src block
    const int scol = gcb * 8;                           // element offset in BK

    for (int k0 = 0; k0 < KPAD; k0 += 64) {
#pragma unroll
        for (int i = 0; i < 4; ++i) {
            int gr = mt * 128 + i * 32 + srow;
            if (gr >= Mrows) gr = 0;
            GLDS16(A + (size_t)gr * KPAD + k0 + scol,
                   ((char*)As) + i * 4096 + tid * 16);
            const int gn = nt * 128 + i * 32 + srow;
            GLDS16(Wb + (size_t)gn * KPAD + k0 + scol,
                   ((char*)Bs) + i * 4096 + tid * 16);
        }
        __syncthreads();

#pragma unroll
        for (int ks = 0; ks < 2; ++ks) {
            const int kb  = (ks * 32 + lk) >> 3;        // 16B-block index 0..7
            const int kel = (kb ^ sb) * 8;              // swizzled element col
            bf16x8 af[4], bf[4];
#pragma unroll
            for (int i = 0; i < 4; ++i)
                af[i] = *(const bf16x8*)&As[(wr * 64 + i * 16 + lr) * 64 + kel];
#pragma unroll
            for (int j = 0; j < 4; ++j)
                bf[j] = *(const bf16x8*)&Bs[(wc * 64 + j * 16 + lr) * 64 + kel];
#pragma unroll
            for (int i = 0; i < 4; ++i)
#pragma unroll
                for (int j = 0; j < 4; ++j)
                    acc[i][j] = __builtin_amdgcn_mfma_f32_16x16x32_bf16(
                        af[i], bf[j], acc[i][j], 0, 0, 0);
        }
        __syncthreads();
    }

    float bn[4];
#pragma unroll
    for (int j = 0; j < 4; ++j)
        bn[j] = bias[nt * 128 + wc * 64 + j * 16 + lr];

#pragma unroll
    for (int i = 0; i < 4; ++i) {
        const int mbase = mt * 128 + wr * 64 + i * 16 + (lane >> 4) * 4;
#pragma unroll
        for (int r = 0; r < 4; ++r) {
            const int m = mbase + r;
            if (m < Mrows) {
#pragma unroll
                for (int j = 0; j < 4; ++j) {
                    const int n = nt * 128 + wc * 64 + j * 16 + lr;
                    out[(size_t)m * ODIM + n] = acc[i][j][r] + bn[j];
                }
            }
        }
    }
}

extern "C" void kernel_launch(void* const* d_in, const int* in_sizes, int n_in,
                              void* d_out, int out_size, void* d_ws, size_t ws_size,
                              hipStream_t stream) {
    const float* inp  = (const float*)d_in[0];
    const float* W    = (const float*)d_in[1];
    const float* bias = (const float*)d_in[2];
    float* out = (float*)d_out;

    const size_t wbBytes = (size_t)ODIM * KPAD * sizeof(unsigned short);
    const size_t sigPB   = (size_t)TSTEPS * KPAD * sizeof(unsigned short); // 2.42 MB
    const size_t ckptPB  = (size_t)15 * NSIG * sizeof(float);              // 0.28 MB
    const size_t perB    = sigPB + ckptPB;

    int nbMax = (int)((ws_size - wbBytes) / perB);
    if (nbMax > BATCH) nbMax = BATCH;
    if (nbMax < 1) nbMax = 1;

    unsigned short* sig  = (unsigned short*)d_ws;
    float*          ckpt = (float*)((char*)d_ws + (size_t)nbMax * sigPB);
    unsigned short* Wb   = (unsigned short*)((char*)d_ws + (ws_size - wbBytes));

    wcvt_kernel<<<(ODIM * KPAD + 255) / 256, 256, 0, stream>>>(W, Wb);

    for (int b0 = 0; b0 < BATCH; b0 += nbMax) {
        const int nb = (b0 + nbMax <= BATCH) ? nbMax : (BATCH - b0);
        const int Mrows = nb * TSTEPS;
        const float* ipb = inp + (size_t)b0 * LSEQ * CIN;
        sig_ckpt_kernel<<<nb, 512, 0, stream>>>(ipb, ckpt);
        sig_write_kernel<<<dim3(NCHUNK, nb), 512, 0, stream>>>(ipb, ckpt, sig);
        gemm_kernel<<<dim3(ODIM / 128, (Mrows + 127) / 128), 256, 0, stream>>>(
            sig, Wb, bias, out + (size_t)b0 * TSTEPS * ODIM, Mrows);
    }
}